// Round 2
// baseline (1157.955 us; speedup 1.0000x reference)
//
#include <hip/hip_runtime.h>

#define BB 32
#define NN 256
#define NF 16
#define NL 3

// ws layout (floats):
//   x0 : [B][N][4]  @ 0        (32768)
//   x1 : [B][N][4]  @ 32768
//   h0 : [B][N][16] @ 65536    (131072)
//   h1 : [B][N][16] @ 196608

__global__ __launch_bounds__(256)
void init_kernel(const float* __restrict__ xs, const float* __restrict__ charges,
                 const float* __restrict__ W_in, const float* __restrict__ b_in,
                 float* __restrict__ x0, float* __restrict__ h0) {
    int n = blockIdx.x * blockDim.x + threadIdx.x;   // 0..B*N-1
    if (n >= BB * NN) return;
    float c = charges[n];
#pragma unroll
    for (int f = 0; f < NF; ++f) {
        h0[n * NF + f] = fmaxf(fmaf(c, W_in[f], b_in[f]), 0.f);
    }
    x0[n * 4 + 0] = xs[n * 3 + 0];
    x0[n * 4 + 1] = xs[n * 3 + 1];
    x0[n * 4 + 2] = xs[n * 3 + 2];
    x0[n * 4 + 3] = 0.f;
}

// 512 blocks x 256 threads. Block = (batch b, 16-dst chunk).
// Thread (d, sl): dst j = dst0+d, srcs 4*sl + 64*ii + {0..3}, ii=0..3.
// Register discipline: only ma..md[16] (64) + aggm[16] live across the k-loop;
// m1, We2 rows, v_j, wr, be2, Wx all consumed as transients / LDS broadcasts.
__global__ __launch_bounds__(256, 2)
void layer_kernel(const float* __restrict__ x_in, const float* __restrict__ h_in,
                  float* __restrict__ x_out, float* __restrict__ h_out,
                  const float* __restrict__ vs,
                  const float* __restrict__ W_v, const float* __restrict__ We1,
                  const float* __restrict__ be1, const float* __restrict__ We2,
                  const float* __restrict__ be2, const float* __restrict__ Wx,
                  const float* __restrict__ Wh1, const float* __restrict__ bh1,
                  int l, int final_layer) {
    __shared__ float4 sx[NN];                       // 4 KB
    __shared__ float  sh[NN][NF + 1];               // 17 KB (pad breaks 16-stride)
    __shared__ float  su[NF][NN];                   // 16 KB, u transposed: su[k][i]
    __shared__ float  svd[16][NF];                  // 1 KB
    __shared__ __align__(16) float sWe2[NF][NF];    // 1 KB
    __shared__ float  sWsrc[NF][NF];                // 1 KB
    __shared__ float  sWdst[NF][NF];                // 1 KB
    __shared__ float  sWh1[2 * NF][NF];             // 2 KB
    __shared__ float  swr[NF], sbe1[NF], sbe2[NF], sWx[NF], sbh1[NF], sWv[NF];

    const int tid   = threadIdx.x;
    const int b     = blockIdx.x >> 4;
    const int chunk = blockIdx.x & 15;
    const int dst0  = chunk * 16;
    const int d     = tid >> 4;      // dst-local 0..15
    const int sl    = tid & 15;      // src lane 0..15
    const int j     = dst0 + d;      // this thread's dst node

    // ---- stage x, h, weights into LDS ----
    const float* xbp = x_in + (size_t)b * NN * 4;
    const float* hbp = h_in + (size_t)b * NN * NF;
    sx[tid] = ((const float4*)xbp)[tid];
    {
        const float4* h4 = (const float4*)hbp;
#pragma unroll
        for (int q = 0; q < 4; ++q) {
            float4 v = h4[tid * 4 + q];
            sh[tid][q * 4 + 0] = v.x;
            sh[tid][q * 4 + 1] = v.y;
            sh[tid][q * 4 + 2] = v.z;
            sh[tid][q * 4 + 3] = v.w;
        }
    }
    const float* pWe1 = We1 + l * (2 * NF + 1) * NF;
    ((float*)sWsrc)[tid] = pWe1[tid];
    ((float*)sWdst)[tid] = pWe1[256 + tid];
    ((float*)sWe2)[tid]  = We2[l * 256 + tid];
    ((float*)sWh1)[tid]        = Wh1[l * 512 + tid];
    ((float*)sWh1)[256 + tid]  = Wh1[l * 512 + 256 + tid];
    if (tid < NF) {
        swr[tid]  = pWe1[512 + tid];
        sbe1[tid] = be1[l * NF + tid];
        sbe2[tid] = be2[l * NF + tid];
        sWx[tid]  = Wx[l * NF + tid];
        sbh1[tid] = bh1[l * NF + tid];
        sWv[tid]  = W_v[l * NF + tid];
    }
    __syncthreads();

    // ---- precompute u_i = h_i @ Wsrc (thread t -> node t), store transposed ----
    {
        float hc[NF];
#pragma unroll
        for (int c = 0; c < NF; ++c) hc[c] = sh[tid][c];
#pragma unroll
        for (int k = 0; k < NF; ++k) {
            float u = 0.f;
#pragma unroll
            for (int c = 0; c < NF; ++c) u = fmaf(hc[c], sWsrc[c][k], u);
            su[k][tid] = u;
        }
    }
    // ---- precompute v_j = be1 + h_j @ Wdst for this block's 16 dsts ----
    {
        int jd = tid >> 4, k = tid & 15;
        int jj = dst0 + jd;
        float v = sbe1[k];
#pragma unroll
        for (int c = 0; c < NF; ++c) v = fmaf(sh[jj][c], sWdst[c][k], v);
        svd[jd][k] = v;
    }
    __syncthreads();

    const float4 xj = sx[j];

    float aggm[NF];
#pragma unroll
    for (int o = 0; o < NF; ++o) aggm[o] = 0.f;
    float ax = 0.f, ay = 0.f, az = 0.f;

    // ---- edge loop: 4 consecutive srcs per group, 4 groups ----
#pragma unroll 1
    for (int ii = 0; ii < 4; ++ii) {
        const int s0 = 4 * sl + 64 * ii;
        float r2a, r2b, r2c, r2d;
        {
            float4 xa = sx[s0], xb4 = sx[s0 + 1], xc4 = sx[s0 + 2], xd4 = sx[s0 + 3];
            float dax = xj.x - xa.x,  day = xj.y - xa.y,  daz = xj.z - xa.z;
            float dbx = xj.x - xb4.x, dby = xj.y - xb4.y, dbz = xj.z - xb4.z;
            float dcx = xj.x - xc4.x, dcy = xj.y - xc4.y, dcz = xj.z - xc4.z;
            float ddx = xj.x - xd4.x, ddy = xj.y - xd4.y, ddz = xj.z - xd4.z;
            r2a = fmaf(dax, dax, fmaf(day, day, daz * daz));
            r2b = fmaf(dbx, dbx, fmaf(dby, dby, dbz * dbz));
            r2c = fmaf(dcx, dcx, fmaf(dcy, dcy, dcz * dcz));
            r2d = fmaf(ddx, ddx, fmaf(ddy, ddy, ddz * ddz));
        }

        float ma[NF], mb[NF], mc[NF], md[NF];
#pragma unroll
        for (int o = 0; o < NF; ++o) { ma[o] = 0.f; mb[o] = 0.f; mc[o] = 0.f; md[o] = 0.f; }

#pragma unroll
        for (int k = 0; k < NF; ++k) {
            const float4 u = *(const float4*)&su[k][s0];
            const float vk = svd[d][k];
            const float wk = swr[k];
            float m1a = fmaxf(fmaf(r2a, wk, u.x + vk), 0.f);
            float m1b = fmaxf(fmaf(r2b, wk, u.y + vk), 0.f);
            float m1c = fmaxf(fmaf(r2c, wk, u.z + vk), 0.f);
            float m1d = fmaxf(fmaf(r2d, wk, u.w + vk), 0.f);
            const float4* w4 = (const float4*)&sWe2[k][0];
#pragma unroll
            for (int q = 0; q < 4; ++q) {
                const float4 w = w4[q];
                ma[4*q+0] = fmaf(m1a, w.x, ma[4*q+0]);
                mb[4*q+0] = fmaf(m1b, w.x, mb[4*q+0]);
                mc[4*q+0] = fmaf(m1c, w.x, mc[4*q+0]);
                md[4*q+0] = fmaf(m1d, w.x, md[4*q+0]);
                ma[4*q+1] = fmaf(m1a, w.y, ma[4*q+1]);
                mb[4*q+1] = fmaf(m1b, w.y, mb[4*q+1]);
                mc[4*q+1] = fmaf(m1c, w.y, mc[4*q+1]);
                md[4*q+1] = fmaf(m1d, w.y, md[4*q+1]);
                ma[4*q+2] = fmaf(m1a, w.z, ma[4*q+2]);
                mb[4*q+2] = fmaf(m1b, w.z, mb[4*q+2]);
                mc[4*q+2] = fmaf(m1c, w.z, mc[4*q+2]);
                md[4*q+2] = fmaf(m1d, w.z, md[4*q+2]);
                ma[4*q+3] = fmaf(m1a, w.w, ma[4*q+3]);
                mb[4*q+3] = fmaf(m1b, w.w, mb[4*q+3]);
                mc[4*q+3] = fmaf(m1c, w.w, mc[4*q+3]);
                md[4*q+3] = fmaf(m1d, w.w, md[4*q+3]);
            }
        }

        float wA = 0.f, wB = 0.f, wC = 0.f, wD = 0.f;
        const float vala = (s0     != j) ? 1.f : 0.f;
        const float valb = (s0 + 1 != j) ? 1.f : 0.f;
        const float valc = (s0 + 2 != j) ? 1.f : 0.f;
        const float vald = (s0 + 3 != j) ? 1.f : 0.f;
#pragma unroll
        for (int o = 0; o < NF; ++o) {
            const float beo = sbe2[o];
            const float xo  = sWx[o];
            float va = fmaxf(ma[o] + beo, 0.f);
            float vb = fmaxf(mb[o] + beo, 0.f);
            float vc = fmaxf(mc[o] + beo, 0.f);
            float vd = fmaxf(md[o] + beo, 0.f);
            wA = fmaf(va, xo, wA);
            wB = fmaf(vb, xo, wB);
            wC = fmaf(vc, xo, wC);
            wD = fmaf(vd, xo, wD);
            aggm[o] = fmaf(va, vala, aggm[o]);
            aggm[o] = fmaf(vb, valb, aggm[o]);
            aggm[o] = fmaf(vc, valc, aggm[o]);
            aggm[o] = fmaf(vd, vald, aggm[o]);
        }
        // coordinate accumulation: reread sx, recompute dvecs (regs freed above)
        {
            float4 xa = sx[s0], xb4 = sx[s0 + 1], xc4 = sx[s0 + 2], xd4 = sx[s0 + 3];
            ax = fmaf(wA, xj.x - xa.x, fmaf(wB, xj.x - xb4.x,
                 fmaf(wC, xj.x - xc4.x, fmaf(wD, xj.x - xd4.x, ax))));
            ay = fmaf(wA, xj.y - xa.y, fmaf(wB, xj.y - xb4.y,
                 fmaf(wC, xj.y - xc4.y, fmaf(wD, xj.y - xd4.y, ay))));
            az = fmaf(wA, xj.z - xa.z, fmaf(wB, xj.z - xb4.z,
                 fmaf(wC, xj.z - xc4.z, fmaf(wD, xj.z - xd4.z, az))));
        }
    }

    // ---- reduce across the 16 lanes of this dst group (butterfly) ----
#pragma unroll
    for (int off = 1; off < 16; off <<= 1) {
#pragma unroll
        for (int o = 0; o < NF; ++o) aggm[o] += __shfl_xor(aggm[o], off, 64);
        ax += __shfl_xor(ax, off, 64);
        ay += __shfl_xor(ay, off, 64);
        az += __shfl_xor(az, off, 64);
    }

    // ---- node updates ----
    float hj[NF];
#pragma unroll
    for (int k = 0; k < NF; ++k) hj[k] = sh[j][k];

    float hv = 0.f;
#pragma unroll
    for (int k = 0; k < NF; ++k) hv = fmaf(hj[k], sWv[k], hv);

    // h update: this lane computes feature f = sl
    float hd = sbh1[sl];
#pragma unroll
    for (int k = 0; k < NF; ++k) hd = fmaf(hj[k], sWh1[k][sl], hd);
#pragma unroll
    for (int k = 0; k < NF; ++k) hd = fmaf(aggm[k], sWh1[NF + k][sl], hd);
    float hnew = hj[sl] + fmaxf(hd, 0.f);
    h_out[((size_t)b * NN + j) * NF + sl] = hnew;

    if (sl < 3) {
        float vcomp = vs[((size_t)b * NN + j) * 3 + sl];
        float xc = (sl == 0) ? xj.x : ((sl == 1) ? xj.y : xj.z);
        float ac = (sl == 0) ? ax : ((sl == 1) ? ay : az);
        float xnew = fmaf(ac, (1.f / 255.f), fmaf(vcomp, hv, xc));
        if (final_layer) x_out[((size_t)b * NN + j) * 3 + sl] = xnew;
        else             x_out[((size_t)b * NN + j) * 4 + sl] = xnew;
    }
    if (!final_layer && sl == 3) x_out[((size_t)b * NN + j) * 4 + 3] = 0.f;
}

extern "C" void kernel_launch(void* const* d_in, const int* in_sizes, int n_in,
                              void* d_out, int out_size, void* d_ws, size_t ws_size,
                              hipStream_t stream) {
    const float* xs      = (const float*)d_in[0];
    const float* vs      = (const float*)d_in[1];
    const float* charges = (const float*)d_in[2];
    const float* W_in    = (const float*)d_in[3];
    const float* b_in    = (const float*)d_in[4];
    const float* W_v     = (const float*)d_in[5];
    const float* We1     = (const float*)d_in[6];
    const float* be1     = (const float*)d_in[7];
    const float* We2     = (const float*)d_in[8];
    const float* be2     = (const float*)d_in[9];
    const float* Wx      = (const float*)d_in[10];
    const float* Wh1     = (const float*)d_in[11];
    const float* bh1     = (const float*)d_in[12];
    // d_in[13]=src, d_in[14]=dst: fully-connected pattern, computed analytically.

    float* ws = (float*)d_ws;
    float* x0 = ws;
    float* x1 = ws + 32768;
    float* h0 = ws + 65536;
    float* h1 = ws + 196608;
    float* out = (float*)d_out;

    hipLaunchKernelGGL(init_kernel, dim3(32), dim3(256), 0, stream,
                       xs, charges, W_in, b_in, x0, h0);
    hipLaunchKernelGGL(layer_kernel, dim3(512), dim3(256), 0, stream,
                       x0, h0, x1, h1, vs, W_v, We1, be1, We2, be2, Wx, Wh1, bh1, 0, 0);
    hipLaunchKernelGGL(layer_kernel, dim3(512), dim3(256), 0, stream,
                       x1, h1, x0, h0, vs, W_v, We1, be1, We2, be2, Wx, Wh1, bh1, 1, 0);
    hipLaunchKernelGGL(layer_kernel, dim3(512), dim3(256), 0, stream,
                       x0, h0, out, h1, vs, W_v, We1, be1, We2, be2, Wx, Wh1, bh1, 2, 1);
}

// Round 3
// 806.756 us; speedup vs baseline: 1.4353x; 1.4353x over previous
//
#include <hip/hip_runtime.h>

#define BB 32
#define NN 256
#define NF 16

// ws layout (floats):
//   x0 : [B][N][4]  @ 0        (32768)
//   x1 : [B][N][4]  @ 32768
//   h0 : [B][N][16] @ 65536    (131072)
//   h1 : [B][N][16] @ 196608

__device__ __forceinline__ float4 f4fma(float s, float4 w, float4 a) {
    a.x = fmaf(s, w.x, a.x); a.y = fmaf(s, w.y, a.y);
    a.z = fmaf(s, w.z, a.z); a.w = fmaf(s, w.w, a.w);
    return a;
}
__device__ __forceinline__ float4 f4relu_add(float4 a, float4 b) {
    float4 r;
    r.x = fmaxf(a.x + b.x, 0.f); r.y = fmaxf(a.y + b.y, 0.f);
    r.z = fmaxf(a.z + b.z, 0.f); r.w = fmaxf(a.w + b.w, 0.f);
    return r;
}
__device__ __forceinline__ float f4dotacc(float4 a, float4 b, float acc) {
    acc = fmaf(a.x, b.x, acc); acc = fmaf(a.y, b.y, acc);
    acc = fmaf(a.z, b.z, acc); acc = fmaf(a.w, b.w, acc);
    return acc;
}
__device__ __forceinline__ float4 f4shflxor_add(float4 v, int off) {
    v.x += __shfl_xor(v.x, off, 64); v.y += __shfl_xor(v.y, off, 64);
    v.z += __shfl_xor(v.z, off, 64); v.w += __shfl_xor(v.w, off, 64);
    return v;
}

__global__ __launch_bounds__(256)
void init_kernel(const float* __restrict__ xs, const float* __restrict__ charges,
                 const float* __restrict__ W_in, const float* __restrict__ b_in,
                 float* __restrict__ x0, float* __restrict__ h0) {
    int n = blockIdx.x * blockDim.x + threadIdx.x;   // 0..B*N-1
    if (n >= BB * NN) return;
    float c = charges[n];
#pragma unroll
    for (int f = 0; f < NF; ++f) {
        h0[n * NF + f] = fmaxf(fmaf(c, W_in[f], b_in[f]), 0.f);
    }
    x0[n * 4 + 0] = xs[n * 3 + 0];
    x0[n * 4 + 1] = xs[n * 3 + 1];
    x0[n * 4 + 2] = xs[n * 3 + 2];
    x0[n * 4 + 3] = 0.f;
}

// One MLP-hidden step for 2 edges: m1 = relu(u + v + r2*wr), acc += m1 * We2row
#define KSTEP(UA, UB, VV, WW, KIDX)                                    \
    {                                                                  \
        const float m1a = fmaxf(fmaf(r2a, (WW), (UA) + (VV)), 0.f);    \
        const float m1b = fmaxf(fmaf(r2b, (WW), (UB) + (VV)), 0.f);    \
        const float4 w0 = we2v[(KIDX) * 4 + 0];                        \
        const float4 w1 = we2v[(KIDX) * 4 + 1];                        \
        const float4 w2 = we2v[(KIDX) * 4 + 2];                        \
        const float4 w3 = we2v[(KIDX) * 4 + 3];                        \
        ma0 = f4fma(m1a, w0, ma0); ma1 = f4fma(m1a, w1, ma1);          \
        ma2 = f4fma(m1a, w2, ma2); ma3 = f4fma(m1a, w3, ma3);          \
        mb0 = f4fma(m1b, w0, mb0); mb1 = f4fma(m1b, w1, mb1);          \
        mb2 = f4fma(m1b, w2, mb2); mb3 = f4fma(m1b, w3, mb3);          \
    }

#define EPIQ(MA, MB, G, Q)                                             \
    {                                                                  \
        const float4 be = sbe4[Q], xw = sWx4[Q];                       \
        const float4 va = f4relu_add(MA, be);                          \
        const float4 vb = f4relu_add(MB, be);                          \
        wA = f4dotacc(va, xw, wA); wB = f4dotacc(vb, xw, wB);          \
        G = f4fma(vala, va, G); G = f4fma(valb, vb, G);                \
    }

// 512 blocks x 256 threads. Block = (batch b, 16-dst chunk).
// Thread (d, sl): dst j = dst0+d; srcs {2*sl, 2*sl+1} + 32*ii, ii=0..7.
// NO indexed local arrays in the hot loop — named float4 accumulators only
// (R2 post-mortem: indexed arrays were lowered to scratch -> 1.1 GB/dispatch).
__global__ __launch_bounds__(256, 2)
void layer_kernel(const float* __restrict__ x_in, const float* __restrict__ h_in,
                  float* __restrict__ x_out, float* __restrict__ h_out,
                  const float* __restrict__ vs,
                  const float* __restrict__ W_v, const float* __restrict__ We1,
                  const float* __restrict__ be1, const float* __restrict__ We2,
                  const float* __restrict__ be2, const float* __restrict__ Wx,
                  const float* __restrict__ Wh1, const float* __restrict__ bh1,
                  int l, int final_layer) {
    __shared__ float4 sx[NN];                         // 4 KB
    __shared__ float  sh[NN][NF + 1];                 // 17 KB
    __shared__ __align__(16) float su[NN][18];        // 18 KB, row stride 18 (72B): float2-aligned, 2-way max aliasing
    __shared__ __align__(16) float svd[16][NF];       // 1 KB
    __shared__ __align__(16) float sWe2[NF][NF];      // 1 KB
    __shared__ float  sWsrc[NF][NF];                  // 1 KB
    __shared__ float  sWdst[NF][NF];                  // 1 KB
    __shared__ float  sWh1[2 * NF][NF];               // 2 KB
    __shared__ __align__(16) float swr[NF];
    __shared__ __align__(16) float sbe2[NF];
    __shared__ __align__(16) float sWx[NF];
    __shared__ float sbe1[NF], sbh1[NF], sWv[NF];

    const int tid  = threadIdx.x;
    const int b    = blockIdx.x >> 4;
    const int dst0 = (blockIdx.x & 15) * 16;
    const int d    = tid >> 4;      // dst-local 0..15
    const int sl   = tid & 15;      // src lane 0..15
    const int j    = dst0 + d;      // this thread's dst node

    // ---- stage x, h, weights into LDS ----
    const float* xbp = x_in + (size_t)b * NN * 4;
    const float* hbp = h_in + (size_t)b * NN * NF;
    sx[tid] = ((const float4*)xbp)[tid];
    {
        const float4* h4 = (const float4*)hbp;
#pragma unroll
        for (int q = 0; q < 4; ++q) {
            float4 v = h4[tid * 4 + q];
            sh[tid][q * 4 + 0] = v.x;
            sh[tid][q * 4 + 1] = v.y;
            sh[tid][q * 4 + 2] = v.z;
            sh[tid][q * 4 + 3] = v.w;
        }
    }
    const float* pWe1 = We1 + l * (2 * NF + 1) * NF;
    ((float*)sWsrc)[tid] = pWe1[tid];
    ((float*)sWdst)[tid] = pWe1[256 + tid];
    ((float*)sWe2)[tid]  = We2[l * 256 + tid];
    ((float*)sWh1)[tid]        = Wh1[l * 512 + tid];
    ((float*)sWh1)[256 + tid]  = Wh1[l * 512 + 256 + tid];
    if (tid < NF) {
        swr[tid]  = pWe1[512 + tid];
        sbe1[tid] = be1[l * NF + tid];
        sbe2[tid] = be2[l * NF + tid];
        sWx[tid]  = Wx[l * NF + tid];
        sbh1[tid] = bh1[l * NF + tid];
        sWv[tid]  = W_v[l * NF + tid];
    }
    __syncthreads();

    // ---- precompute u_i = h_i @ Wsrc (thread t -> node t) ----
    {
        float hc[NF];
#pragma unroll
        for (int c = 0; c < NF; ++c) hc[c] = sh[tid][c];
#pragma unroll
        for (int k = 0; k < NF; ++k) {
            float u = 0.f;
#pragma unroll
            for (int c = 0; c < NF; ++c) u = fmaf(hc[c], sWsrc[c][k], u);
            su[tid][k] = u;
        }
    }
    // ---- precompute v_j = be1 + h_j @ Wdst for this block's 16 dsts ----
    {
        int jd = tid >> 4, k = tid & 15;
        int jj = dst0 + jd;
        float v = sbe1[k];
#pragma unroll
        for (int c = 0; c < NF; ++c) v = fmaf(sh[jj][c], sWdst[c][k], v);
        svd[jd][k] = v;
    }
    __syncthreads();

    const float4 xj = sx[j];
    const float4* we2v = (const float4*)sWe2;
    const float4* svd4 = (const float4*)&svd[d][0];
    const float4* swr4 = (const float4*)swr;
    const float4* sbe4 = (const float4*)sbe2;
    const float4* sWx4 = (const float4*)sWx;

    float4 g0 = make_float4(0.f, 0.f, 0.f, 0.f);
    float4 g1 = g0, g2 = g0, g3 = g0;
    float ax = 0.f, ay = 0.f, az = 0.f;

    // ---- edge loop: 2 consecutive srcs per step, 8 steps ----
#pragma unroll 1
    for (int ii = 0; ii < 8; ++ii) {
        const int sa = 2 * sl + 32 * ii;
        const int sb = sa + 1;
        const float4 xa = sx[sa];
        const float4 xb = sx[sb];
        const float dax = xj.x - xa.x, day = xj.y - xa.y, daz = xj.z - xa.z;
        const float dbx = xj.x - xb.x, dby = xj.y - xb.y, dbz = xj.z - xb.z;
        const float r2a = fmaf(dax, dax, fmaf(day, day, daz * daz));
        const float r2b = fmaf(dbx, dbx, fmaf(dby, dby, dbz * dbz));

        const float2* suA = (const float2*)&su[sa][0];
        const float2* suB = (const float2*)&su[sb][0];

        float4 ma0 = make_float4(0.f, 0.f, 0.f, 0.f);
        float4 ma1 = ma0, ma2 = ma0, ma3 = ma0;
        float4 mb0 = ma0, mb1 = ma0, mb2 = ma0, mb3 = ma0;

#pragma unroll
        for (int q = 0; q < 4; ++q) {
            const float4 vq = svd4[q];
            const float4 wq = swr4[q];
            const float2 ua01 = suA[2 * q], ua23 = suA[2 * q + 1];
            const float2 ub01 = suB[2 * q], ub23 = suB[2 * q + 1];
            KSTEP(ua01.x, ub01.x, vq.x, wq.x, 4 * q + 0)
            KSTEP(ua01.y, ub01.y, vq.y, wq.y, 4 * q + 1)
            KSTEP(ua23.x, ub23.x, vq.z, wq.z, 4 * q + 2)
            KSTEP(ua23.y, ub23.y, vq.w, wq.w, 4 * q + 3)
        }

        const float vala = (sa != j) ? 1.f : 0.f;
        const float valb = (sb != j) ? 1.f : 0.f;
        float wA = 0.f, wB = 0.f;
        EPIQ(ma0, mb0, g0, 0)
        EPIQ(ma1, mb1, g1, 1)
        EPIQ(ma2, mb2, g2, 2)
        EPIQ(ma3, mb3, g3, 3)

        ax = fmaf(wA, dax, fmaf(wB, dbx, ax));
        ay = fmaf(wA, day, fmaf(wB, dby, ay));
        az = fmaf(wA, daz, fmaf(wB, dbz, az));
    }

    // ---- reduce across the 16 lanes of this dst group (butterfly) ----
#pragma unroll
    for (int off = 1; off < 16; off <<= 1) {
        g0 = f4shflxor_add(g0, off);
        g1 = f4shflxor_add(g1, off);
        g2 = f4shflxor_add(g2, off);
        g3 = f4shflxor_add(g3, off);
        ax += __shfl_xor(ax, off, 64);
        ay += __shfl_xor(ay, off, 64);
        az += __shfl_xor(az, off, 64);
    }

    // ---- node updates ----
    float hv = 0.f;
    float hd = sbh1[sl];
#pragma unroll
    for (int k = 0; k < NF; ++k) {
        const float hjk = sh[j][k];
        hv = fmaf(hjk, sWv[k], hv);
        hd = fmaf(hjk, sWh1[k][sl], hd);
    }
    hd = fmaf(g0.x, sWh1[16][sl], hd);
    hd = fmaf(g0.y, sWh1[17][sl], hd);
    hd = fmaf(g0.z, sWh1[18][sl], hd);
    hd = fmaf(g0.w, sWh1[19][sl], hd);
    hd = fmaf(g1.x, sWh1[20][sl], hd);
    hd = fmaf(g1.y, sWh1[21][sl], hd);
    hd = fmaf(g1.z, sWh1[22][sl], hd);
    hd = fmaf(g1.w, sWh1[23][sl], hd);
    hd = fmaf(g2.x, sWh1[24][sl], hd);
    hd = fmaf(g2.y, sWh1[25][sl], hd);
    hd = fmaf(g2.z, sWh1[26][sl], hd);
    hd = fmaf(g2.w, sWh1[27][sl], hd);
    hd = fmaf(g3.x, sWh1[28][sl], hd);
    hd = fmaf(g3.y, sWh1[29][sl], hd);
    hd = fmaf(g3.z, sWh1[30][sl], hd);
    hd = fmaf(g3.w, sWh1[31][sl], hd);
    const float hnew = sh[j][sl] + fmaxf(hd, 0.f);
    h_out[((size_t)b * NN + j) * NF + sl] = hnew;

    if (sl < 3) {
        float vcomp = vs[((size_t)b * NN + j) * 3 + sl];
        float xc = (sl == 0) ? xj.x : ((sl == 1) ? xj.y : xj.z);
        float ac = (sl == 0) ? ax : ((sl == 1) ? ay : az);
        float xnew = fmaf(ac, (1.f / 255.f), fmaf(vcomp, hv, xc));
        if (final_layer) x_out[((size_t)b * NN + j) * 3 + sl] = xnew;
        else             x_out[((size_t)b * NN + j) * 4 + sl] = xnew;
    }
    if (!final_layer && sl == 3) x_out[((size_t)b * NN + j) * 4 + 3] = 0.f;
}

extern "C" void kernel_launch(void* const* d_in, const int* in_sizes, int n_in,
                              void* d_out, int out_size, void* d_ws, size_t ws_size,
                              hipStream_t stream) {
    const float* xs      = (const float*)d_in[0];
    const float* vs      = (const float*)d_in[1];
    const float* charges = (const float*)d_in[2];
    const float* W_in    = (const float*)d_in[3];
    const float* b_in    = (const float*)d_in[4];
    const float* W_v     = (const float*)d_in[5];
    const float* We1     = (const float*)d_in[6];
    const float* be1     = (const float*)d_in[7];
    const float* We2     = (const float*)d_in[8];
    const float* be2     = (const float*)d_in[9];
    const float* Wx      = (const float*)d_in[10];
    const float* Wh1     = (const float*)d_in[11];
    const float* bh1     = (const float*)d_in[12];
    // d_in[13]=src, d_in[14]=dst: fully-connected pattern, computed analytically.

    float* ws = (float*)d_ws;
    float* x0 = ws;
    float* x1 = ws + 32768;
    float* h0 = ws + 65536;
    float* h1 = ws + 196608;
    float* out = (float*)d_out;

    hipLaunchKernelGGL(init_kernel, dim3(32), dim3(256), 0, stream,
                       xs, charges, W_in, b_in, x0, h0);
    hipLaunchKernelGGL(layer_kernel, dim3(512), dim3(256), 0, stream,
                       x0, h0, x1, h1, vs, W_v, We1, be1, We2, be2, Wx, Wh1, bh1, 0, 0);
    hipLaunchKernelGGL(layer_kernel, dim3(512), dim3(256), 0, stream,
                       x1, h1, x0, h0, vs, W_v, We1, be1, We2, be2, Wx, Wh1, bh1, 1, 0);
    hipLaunchKernelGGL(layer_kernel, dim3(512), dim3(256), 0, stream,
                       x0, h0, out, h1, vs, W_v, We1, be1, We2, be2, Wx, Wh1, bh1, 2, 1);
}

// Round 4
// 646.230 us; speedup vs baseline: 1.7919x; 1.2484x over previous
//
#include <hip/hip_runtime.h>

#define BB 32
#define NN 256
#define NF 16

// ws layout (floats):
//   x0 : [B][N][4]  @ 0        (32768)
//   x1 : [B][N][4]  @ 32768
//   h0 : [B][N][16] @ 65536    (131072)
//   h1 : [B][N][16] @ 196608

__global__ __launch_bounds__(256)
void init_kernel(const float* __restrict__ xs, const float* __restrict__ charges,
                 const float* __restrict__ W_in, const float* __restrict__ b_in,
                 float* __restrict__ x0, float* __restrict__ h0) {
    int n = blockIdx.x * blockDim.x + threadIdx.x;   // 0..B*N-1
    if (n >= BB * NN) return;
    float c = charges[n];
#pragma unroll
    for (int f = 0; f < NF; ++f) {
        h0[n * NF + f] = fmaxf(fmaf(c, W_in[f], b_in[f]), 0.f);
    }
    x0[n * 4 + 0] = xs[n * 3 + 0];
    x0[n * 4 + 1] = xs[n * 3 + 1];
    x0[n * 4 + 2] = xs[n * 3 + 2];
    x0[n * 4 + 3] = 0.f;
}

// Load one We2 row (row KIDX) into the four transient float4s wa..wd.
#define WROW(K) \
    wa = we2v[(K)*4+0]; wb = we2v[(K)*4+1]; wc = we2v[(K)*4+2]; wd = we2v[(K)*4+3];

#define ACCI(T) \
    m0=(T)*wa.x;  m1=(T)*wa.y;  m2=(T)*wa.z;  m3=(T)*wa.w;  \
    m4=(T)*wb.x;  m5=(T)*wb.y;  m6=(T)*wb.z;  m7=(T)*wb.w;  \
    m8=(T)*wc.x;  m9=(T)*wc.y;  m10=(T)*wc.z; m11=(T)*wc.w; \
    m12=(T)*wd.x; m13=(T)*wd.y; m14=(T)*wd.z; m15=(T)*wd.w;

#define ACCA(T) \
    m0=fmaf((T),wa.x,m0);   m1=fmaf((T),wa.y,m1);   m2=fmaf((T),wa.z,m2);   m3=fmaf((T),wa.w,m3);  \
    m4=fmaf((T),wb.x,m4);   m5=fmaf((T),wb.y,m5);   m6=fmaf((T),wb.z,m6);   m7=fmaf((T),wb.w,m7);  \
    m8=fmaf((T),wc.x,m8);   m9=fmaf((T),wc.y,m9);   m10=fmaf((T),wc.z,m10); m11=fmaf((T),wc.w,m11);\
    m12=fmaf((T),wd.x,m12); m13=fmaf((T),wd.y,m13); m14=fmaf((T),wd.z,m14); m15=fmaf((T),wd.w,m15);

// One k-step: m1k = relu(u + v + r2*wr), then rank-1 accumulate into m0..m15.
#define KST(UU, VV, WW, KIDX, HOW) { \
    const float t1 = fmaxf(fmaf(r2, (WW), (UU) + (VV)), 0.f); \
    WROW(KIDX) \
    HOW(t1) }

// Epilogue for one quad of outputs: relu(m+be2), dot with Wx, masked aggm.
#define EPI4(MA, MB, MC, MD, GA, GB, GC, GD, Q) { \
    const float4 be = sbe4[Q]; const float4 xw = sWx4[Q]; float t; \
    t = fmaxf((MA)+be.x, 0.f); wsum = fmaf(t, xw.x, wsum); GA = fmaf(t, val, GA); \
    t = fmaxf((MB)+be.y, 0.f); wsum = fmaf(t, xw.y, wsum); GB = fmaf(t, val, GB); \
    t = fmaxf((MC)+be.z, 0.f); wsum = fmaf(t, xw.z, wsum); GC = fmaf(t, val, GC); \
    t = fmaxf((MD)+be.w, 0.f); wsum = fmaf(t, xw.w, wsum); GD = fmaf(t, val, GD); }

// 512 blocks x 256 threads. Block = (batch b, 16-dst chunk).
// Thread (d, sl): dst j = dst0+d; ONE edge per iteration, src s = sl + 16*ii.
// ALL hot-loop accumulators are individually named scalar floats — no arrays,
// no float4 accumulators (R1-R3 post-mortems: both forms were lowered to
// scratch, ~1 GB/dispatch HBM traffic, VGPR pinned at the 128 tier).
__global__ __launch_bounds__(256, 2)
void layer_kernel(const float* __restrict__ x_in, const float* __restrict__ h_in,
                  float* __restrict__ x_out, float* __restrict__ h_out,
                  const float* __restrict__ vs,
                  const float* __restrict__ W_v, const float* __restrict__ We1,
                  const float* __restrict__ be1, const float* __restrict__ We2,
                  const float* __restrict__ be2, const float* __restrict__ Wx,
                  const float* __restrict__ Wh1, const float* __restrict__ bh1,
                  int l, int final_layer) {
    __shared__ float4 sx[NN];                         // 4 KB
    __shared__ float  sh[NN][NF + 1];                 // 17 KB
    __shared__ __align__(16) float su[NN][20];        // 20 KB; stride 20 floats = 80 B: rows 16B-aligned, 2-way bank aliasing (free)
    __shared__ __align__(16) float svd[16][NF];       // 1 KB
    __shared__ __align__(16) float sWe2[NF][NF];      // 1 KB
    __shared__ float  sWsrc[NF][NF];                  // 1 KB
    __shared__ float  sWdst[NF][NF];                  // 1 KB
    __shared__ float  sWh1[2 * NF][NF];               // 2 KB
    __shared__ __align__(16) float swr[NF];
    __shared__ __align__(16) float sbe2[NF];
    __shared__ __align__(16) float sWx[NF];
    __shared__ float sbe1[NF], sbh1[NF], sWv[NF];

    const int tid  = threadIdx.x;
    const int b    = blockIdx.x >> 4;
    const int dst0 = (blockIdx.x & 15) * 16;
    const int d    = tid >> 4;      // dst-local 0..15
    const int sl   = tid & 15;      // src lane 0..15
    const int j    = dst0 + d;      // this thread's dst node

    // ---- stage x, h, weights into LDS ----
    const float* xbp = x_in + (size_t)b * NN * 4;
    const float* hbp = h_in + (size_t)b * NN * NF;
    sx[tid] = ((const float4*)xbp)[tid];
    {
        const float4* h4 = (const float4*)hbp;
#pragma unroll
        for (int q = 0; q < 4; ++q) {
            float4 v = h4[tid * 4 + q];
            sh[tid][q * 4 + 0] = v.x;
            sh[tid][q * 4 + 1] = v.y;
            sh[tid][q * 4 + 2] = v.z;
            sh[tid][q * 4 + 3] = v.w;
        }
    }
    const float* pWe1 = We1 + l * (2 * NF + 1) * NF;
    ((float*)sWsrc)[tid] = pWe1[tid];
    ((float*)sWdst)[tid] = pWe1[256 + tid];
    ((float*)sWe2)[tid]  = We2[l * 256 + tid];
    ((float*)sWh1)[tid]        = Wh1[l * 512 + tid];
    ((float*)sWh1)[256 + tid]  = Wh1[l * 512 + 256 + tid];
    if (tid < NF) {
        swr[tid]  = pWe1[512 + tid];
        sbe1[tid] = be1[l * NF + tid];
        sbe2[tid] = be2[l * NF + tid];
        sWx[tid]  = Wx[l * NF + tid];
        sbh1[tid] = bh1[l * NF + tid];
        sWv[tid]  = W_v[l * NF + tid];
    }
    __syncthreads();

    // ---- precompute u_i = h_i @ Wsrc (thread t -> node t) ----
    {
        float hc[NF];
#pragma unroll
        for (int c = 0; c < NF; ++c) hc[c] = sh[tid][c];
#pragma unroll
        for (int k = 0; k < NF; ++k) {
            float u = 0.f;
#pragma unroll
            for (int c = 0; c < NF; ++c) u = fmaf(hc[c], sWsrc[c][k], u);
            su[tid][k] = u;
        }
    }
    // ---- precompute v_j = be1 + h_j @ Wdst for this block's 16 dsts ----
    {
        int jd = tid >> 4, k = tid & 15;
        int jj = dst0 + jd;
        float v = sbe1[k];
#pragma unroll
        for (int c = 0; c < NF; ++c) v = fmaf(sh[jj][c], sWdst[c][k], v);
        svd[jd][k] = v;
    }
    __syncthreads();

    const float xjx = sx[j].x, xjy = sx[j].y, xjz = sx[j].z;
    const float4* we2v = (const float4*)sWe2;
    const float4* svd4 = (const float4*)&svd[d][0];
    const float4* swr4 = (const float4*)swr;
    const float4* sbe4 = (const float4*)sbe2;
    const float4* sWx4 = (const float4*)sWx;

    float g0=0.f,g1=0.f,g2=0.f,g3=0.f,g4=0.f,g5=0.f,g6=0.f,g7=0.f;
    float g8=0.f,g9=0.f,g10=0.f,g11=0.f,g12=0.f,g13=0.f,g14=0.f,g15=0.f;
    float ax = 0.f, ay = 0.f, az = 0.f;

    // ---- edge loop: ONE src per iteration, 16 iterations ----
#pragma unroll 1
    for (int ii = 0; ii < 16; ++ii) {
        const int s = sl + 16 * ii;
        const float4 xi = sx[s];
        const float dx = xjx - xi.x, dy = xjy - xi.y, dz = xjz - xi.z;
        const float r2 = fmaf(dx, dx, fmaf(dy, dy, dz * dz));

        float m0,m1,m2,m3,m4,m5,m6,m7,m8,m9,m10,m11,m12,m13,m14,m15;
        float4 wa, wb, wc, wd;
        {
            const float4 u4 = *(const float4*)(&su[s][0]);
            const float4 v4 = svd4[0];
            const float4 w4 = swr4[0];
            KST(u4.x, v4.x, w4.x, 0, ACCI)
            KST(u4.y, v4.y, w4.y, 1, ACCA)
            KST(u4.z, v4.z, w4.z, 2, ACCA)
            KST(u4.w, v4.w, w4.w, 3, ACCA)
        }
        {
            const float4 u4 = *(const float4*)(&su[s][4]);
            const float4 v4 = svd4[1];
            const float4 w4 = swr4[1];
            KST(u4.x, v4.x, w4.x, 4, ACCA)
            KST(u4.y, v4.y, w4.y, 5, ACCA)
            KST(u4.z, v4.z, w4.z, 6, ACCA)
            KST(u4.w, v4.w, w4.w, 7, ACCA)
        }
        {
            const float4 u4 = *(const float4*)(&su[s][8]);
            const float4 v4 = svd4[2];
            const float4 w4 = swr4[2];
            KST(u4.x, v4.x, w4.x, 8, ACCA)
            KST(u4.y, v4.y, w4.y, 9, ACCA)
            KST(u4.z, v4.z, w4.z, 10, ACCA)
            KST(u4.w, v4.w, w4.w, 11, ACCA)
        }
        {
            const float4 u4 = *(const float4*)(&su[s][12]);
            const float4 v4 = svd4[3];
            const float4 w4 = swr4[3];
            KST(u4.x, v4.x, w4.x, 12, ACCA)
            KST(u4.y, v4.y, w4.y, 13, ACCA)
            KST(u4.z, v4.z, w4.z, 14, ACCA)
            KST(u4.w, v4.w, w4.w, 15, ACCA)
        }

        const float val = (s != j) ? 1.f : 0.f;
        float wsum = 0.f;
        EPI4(m0,  m1,  m2,  m3,  g0,  g1,  g2,  g3,  0)
        EPI4(m4,  m5,  m6,  m7,  g4,  g5,  g6,  g7,  1)
        EPI4(m8,  m9,  m10, m11, g8,  g9,  g10, g11, 2)
        EPI4(m12, m13, m14, m15, g12, g13, g14, g15, 3)

        ax = fmaf(wsum, dx, ax);
        ay = fmaf(wsum, dy, ay);
        az = fmaf(wsum, dz, az);
    }

    // ---- reduce across the 16 lanes of this dst group (butterfly) ----
#pragma unroll
    for (int off = 1; off < 16; off <<= 1) {
        g0  += __shfl_xor(g0,  off, 64);  g1  += __shfl_xor(g1,  off, 64);
        g2  += __shfl_xor(g2,  off, 64);  g3  += __shfl_xor(g3,  off, 64);
        g4  += __shfl_xor(g4,  off, 64);  g5  += __shfl_xor(g5,  off, 64);
        g6  += __shfl_xor(g6,  off, 64);  g7  += __shfl_xor(g7,  off, 64);
        g8  += __shfl_xor(g8,  off, 64);  g9  += __shfl_xor(g9,  off, 64);
        g10 += __shfl_xor(g10, off, 64);  g11 += __shfl_xor(g11, off, 64);
        g12 += __shfl_xor(g12, off, 64);  g13 += __shfl_xor(g13, off, 64);
        g14 += __shfl_xor(g14, off, 64);  g15 += __shfl_xor(g15, off, 64);
        ax += __shfl_xor(ax, off, 64);
        ay += __shfl_xor(ay, off, 64);
        az += __shfl_xor(az, off, 64);
    }

    // ---- node updates ----
    float hv = 0.f;
    float hd = sbh1[sl];
#pragma unroll
    for (int k = 0; k < NF; ++k) {
        const float hjk = sh[j][k];
        hv = fmaf(hjk, sWv[k], hv);
        hd = fmaf(hjk, sWh1[k][sl], hd);
    }
    hd = fmaf(g0,  sWh1[16][sl], hd);
    hd = fmaf(g1,  sWh1[17][sl], hd);
    hd = fmaf(g2,  sWh1[18][sl], hd);
    hd = fmaf(g3,  sWh1[19][sl], hd);
    hd = fmaf(g4,  sWh1[20][sl], hd);
    hd = fmaf(g5,  sWh1[21][sl], hd);
    hd = fmaf(g6,  sWh1[22][sl], hd);
    hd = fmaf(g7,  sWh1[23][sl], hd);
    hd = fmaf(g8,  sWh1[24][sl], hd);
    hd = fmaf(g9,  sWh1[25][sl], hd);
    hd = fmaf(g10, sWh1[26][sl], hd);
    hd = fmaf(g11, sWh1[27][sl], hd);
    hd = fmaf(g12, sWh1[28][sl], hd);
    hd = fmaf(g13, sWh1[29][sl], hd);
    hd = fmaf(g14, sWh1[30][sl], hd);
    hd = fmaf(g15, sWh1[31][sl], hd);
    const float hnew = sh[j][sl] + fmaxf(hd, 0.f);
    h_out[((size_t)b * NN + j) * NF + sl] = hnew;

    if (sl < 3) {
        float vcomp = vs[((size_t)b * NN + j) * 3 + sl];
        float xc = (sl == 0) ? xjx : ((sl == 1) ? xjy : xjz);
        float ac = (sl == 0) ? ax : ((sl == 1) ? ay : az);
        float xnew = fmaf(ac, (1.f / 255.f), fmaf(vcomp, hv, xc));
        if (final_layer) x_out[((size_t)b * NN + j) * 3 + sl] = xnew;
        else             x_out[((size_t)b * NN + j) * 4 + sl] = xnew;
    }
    if (!final_layer && sl == 3) x_out[((size_t)b * NN + j) * 4 + 3] = 0.f;
}

extern "C" void kernel_launch(void* const* d_in, const int* in_sizes, int n_in,
                              void* d_out, int out_size, void* d_ws, size_t ws_size,
                              hipStream_t stream) {
    const float* xs      = (const float*)d_in[0];
    const float* vs      = (const float*)d_in[1];
    const float* charges = (const float*)d_in[2];
    const float* W_in    = (const float*)d_in[3];
    const float* b_in    = (const float*)d_in[4];
    const float* W_v     = (const float*)d_in[5];
    const float* We1     = (const float*)d_in[6];
    const float* be1     = (const float*)d_in[7];
    const float* We2     = (const float*)d_in[8];
    const float* be2     = (const float*)d_in[9];
    const float* Wx      = (const float*)d_in[10];
    const float* Wh1     = (const float*)d_in[11];
    const float* bh1     = (const float*)d_in[12];
    // d_in[13]=src, d_in[14]=dst: fully-connected pattern, computed analytically.

    float* ws = (float*)d_ws;
    float* x0 = ws;
    float* x1 = ws + 32768;
    float* h0 = ws + 65536;
    float* h1 = ws + 196608;
    float* out = (float*)d_out;

    hipLaunchKernelGGL(init_kernel, dim3(32), dim3(256), 0, stream,
                       xs, charges, W_in, b_in, x0, h0);
    hipLaunchKernelGGL(layer_kernel, dim3(512), dim3(256), 0, stream,
                       x0, h0, x1, h1, vs, W_v, We1, be1, We2, be2, Wx, Wh1, bh1, 0, 0);
    hipLaunchKernelGGL(layer_kernel, dim3(512), dim3(256), 0, stream,
                       x1, h1, x0, h0, vs, W_v, We1, be1, We2, be2, Wx, Wh1, bh1, 1, 0);
    hipLaunchKernelGGL(layer_kernel, dim3(512), dim3(256), 0, stream,
                       x0, h0, out, h1, vs, W_v, We1, be1, We2, be2, Wx, Wh1, bh1, 2, 1);
}

// Round 5
// 156.498 us; speedup vs baseline: 7.3992x; 4.1293x over previous
//
#include <hip/hip_runtime.h>

#define BB 32
#define NN 256
#define NF 16

typedef _Float16 half4 __attribute__((ext_vector_type(4)));
typedef float f32x4 __attribute__((ext_vector_type(4)));

// ws layout (floats):
//   x0 : [B][N][4]  @ 0        (32768)
//   x1 : [B][N][4]  @ 32768
//   h0 : [B][N][16] @ 65536    (131072)
//   h1 : [B][N][16] @ 196608

__global__ __launch_bounds__(256)
void init_kernel(const float* __restrict__ xs, const float* __restrict__ charges,
                 const float* __restrict__ W_in, const float* __restrict__ b_in,
                 float* __restrict__ x0, float* __restrict__ h0) {
    int n = blockIdx.x * blockDim.x + threadIdx.x;   // 0..B*N-1
    if (n >= BB * NN) return;
    float c = charges[n];
#pragma unroll
    for (int f = 0; f < NF; ++f) {
        h0[n * NF + f] = fmaxf(fmaf(c, W_in[f], b_in[f]), 0.f);
    }
    x0[n * 4 + 0] = xs[n * 3 + 0];
    x0[n * 4 + 1] = xs[n * 3 + 1];
    x0[n * 4 + 2] = xs[n * 3 + 2];
    x0[n * 4 + 3] = 0.f;
}

__device__ __forceinline__ float dot4(float4 a, float4 b, float acc) {
    acc = fmaf(a.x, b.x, acc); acc = fmaf(a.y, b.y, acc);
    acc = fmaf(a.z, b.z, acc); acc = fmaf(a.w, b.w, acc);
    return acc;
}

// 2048 blocks x 256 threads. Block = (batch b, dst-quad dg). Wave w owns dst
// j = 4*dg + w. Per 16-src tile: one v_mfma_f32_16x16x16f16 computes
// m-hat = We2^T @ m1^T; lane (g = lane>>4, c = lane&15) holds:
//   B-frag: m1[src=16t+c][k=4g+i]  (built in VALU from u + v_j + r2*wr)
//   A-frag: We2[k=4g+i][outfeat=c] (invariant, 2 VGPRs — the fix for the
//           R1-R4 scratch catastrophe: We2 never lives in one thread's regs)
//   C-frag: m-hat[outfeat=4g+r][src=c]
// Self-edge: masked in g only (w-path self-term cancels exactly in
// Sw*xj - Swx since x_self == xj bitwise).
__global__ __launch_bounds__(256)
void layer_kernel(const float* __restrict__ x_in, const float* __restrict__ h_in,
                  float* __restrict__ x_out, float* __restrict__ h_out,
                  const float* __restrict__ vs, const float* __restrict__ W_v,
                  const float* __restrict__ We1, const float* __restrict__ be1,
                  const float* __restrict__ We2, const float* __restrict__ be2,
                  const float* __restrict__ Wx, const float* __restrict__ Wh1,
                  const float* __restrict__ bh1, int l, int final_layer) {
    __shared__ __align__(16) float4 sx[NN];          // 4 KB
    __shared__ __align__(16) float  su[NN][20];      // 20 KB (rows 80 B: 16B-aligned, 2-way bank alias = free)
    __shared__ __align__(16) float  sWsrcT[NF][NF];  // We1 src block, transposed [k][c]
    __shared__ __align__(16) float  sWdstT[NF][NF];  // We1 dst block, transposed [k][c]
    __shared__ float  sWh1[2 * NF][NF];              // 2 KB
    __shared__ __align__(16) float  shj[4][NF];      // block's 4 dst h vectors
    __shared__ __align__(16) float  svd[4][NF];      // v_j = be1 + h_j @ Wdst
    __shared__ float  sg[4][NF];                     // per-wave g staging

    const int tid  = threadIdx.x;
    const int b    = blockIdx.x >> 6;
    const int dg   = blockIdx.x & 63;
    const int w    = tid >> 6;       // wave 0..3
    const int lane = tid & 63;
    const int c    = lane & 15;
    const int g    = lane >> 4;

    const float* pWe1 = We1 + l * (2 * NF + 1) * NF;

    // ---- phase A: stage ----
    sx[tid] = ((const float4*)(x_in + (size_t)b * NN * 4))[tid];
    {
        const int cc = tid >> 4, k = tid & 15;       // tid = cc*16 + k
        sWsrcT[k][cc] = pWe1[tid];
        sWdstT[k][cc] = pWe1[256 + tid];
    }
    ((float*)sWh1)[tid]       = Wh1[l * 512 + tid];
    ((float*)sWh1)[256 + tid] = Wh1[l * 512 + 256 + tid];
    if (tid < 64) {
        const int jd = tid >> 4, k = tid & 15;
        shj[jd][k] = h_in[((size_t)b * NN + 4 * dg + jd) * NF + k];
    }
    __syncthreads();

    // ---- phase B: u_i = h_i @ Wsrc (thread = node), row-contiguous weight reads ----
    {
        const float4* h4 = (const float4*)(h_in + (size_t)b * NN * NF);
        const float4 q0 = h4[tid * 4 + 0], q1 = h4[tid * 4 + 1];
        const float4 q2 = h4[tid * 4 + 2], q3 = h4[tid * 4 + 3];
#pragma unroll
        for (int k = 0; k < NF; ++k) {
            const float4* wt = (const float4*)&sWsrcT[k][0];
            float u = dot4(q0, wt[0], 0.f);
            u = dot4(q1, wt[1], u);
            u = dot4(q2, wt[2], u);
            u = dot4(q3, wt[3], u);
            su[tid][k] = u;
        }
    }
    if (tid < 64) {
        const int jd = tid >> 4, k = tid & 15;
        const float4* hj4 = (const float4*)&shj[jd][0];
        const float4* wt  = (const float4*)&sWdstT[k][0];
        float v = be1[l * NF + k];
        v = dot4(hj4[0], wt[0], v);
        v = dot4(hj4[1], wt[1], v);
        v = dot4(hj4[2], wt[2], v);
        v = dot4(hj4[3], wt[3], v);
        svd[jd][k] = v;
    }
    __syncthreads();

    // ---- per-wave dst setup ----
    const int j = 4 * dg + w;
    const float4 xj = sx[j];
    const float* We2l = We2 + l * 256;
    half4 afrag;
    afrag.x = (_Float16)We2l[(4 * g + 0) * 16 + c];
    afrag.y = (_Float16)We2l[(4 * g + 1) * 16 + c];
    afrag.z = (_Float16)We2l[(4 * g + 2) * 16 + c];
    afrag.w = (_Float16)We2l[(4 * g + 3) * 16 + c];
    const float4 v4   = *(const float4*)&svd[w][4 * g];
    const float4 wr4  = *(const float4*)&pWe1[512 + 4 * g];
    const float4 be2f = *(const float4*)&be2[l * NF + 4 * g];
    const float4 wxf  = *(const float4*)&Wx[l * NF + 4 * g];

    float Sw = 0.f, Swx = 0.f, Swy = 0.f, Swz = 0.f;
    float g0 = 0.f, g1 = 0.f, g2 = 0.f, g3 = 0.f;

    // ---- 16 src-tiles ----
#pragma unroll 1
    for (int t = 0; t < 16; ++t) {
        const int s = 16 * t + c;
        const float4 xs4 = sx[s];
        const float dx = xj.x - xs4.x, dy = xj.y - xs4.y, dz = xj.z - xs4.z;
        const float r2 = fmaf(dx, dx, fmaf(dy, dy, dz * dz));
        const float4 u4 = *(const float4*)&su[s][4 * g];
        const float m0 = fmaxf(fmaf(r2, wr4.x, u4.x + v4.x), 0.f);
        const float m1 = fmaxf(fmaf(r2, wr4.y, u4.y + v4.y), 0.f);
        const float m2 = fmaxf(fmaf(r2, wr4.z, u4.z + v4.z), 0.f);
        const float m3 = fmaxf(fmaf(r2, wr4.w, u4.w + v4.w), 0.f);
        half4 bfrag;
        bfrag.x = (_Float16)m0; bfrag.y = (_Float16)m1;
        bfrag.z = (_Float16)m2; bfrag.w = (_Float16)m3;
        const f32x4 zc = {0.f, 0.f, 0.f, 0.f};
        const f32x4 acc = __builtin_amdgcn_mfma_f32_16x16x16f16(afrag, bfrag, zc, 0, 0, 0);
        const float e0 = fmaxf(acc.x + be2f.x, 0.f);
        const float e1 = fmaxf(acc.y + be2f.y, 0.f);
        const float e2 = fmaxf(acc.z + be2f.z, 0.f);
        const float e3 = fmaxf(acc.w + be2f.w, 0.f);
        // w partial over this group's 4 out-features, then group-reduce
        float wp = e0 * wxf.x;
        wp = fmaf(e1, wxf.y, wp);
        wp = fmaf(e2, wxf.z, wp);
        wp = fmaf(e3, wxf.w, wp);
        wp += __shfl_xor(wp, 16, 64);
        wp += __shfl_xor(wp, 32, 64);        // w[src 16t+c], replicated over groups
        const float gsel = (s != j) ? 1.f : 0.f;
        g0 = fmaf(e0, gsel, g0);
        g1 = fmaf(e1, gsel, g1);
        g2 = fmaf(e2, gsel, g2);
        g3 = fmaf(e3, gsel, g3);
        Sw += wp;
        Swx = fmaf(wp, xs4.x, Swx);
        Swy = fmaf(wp, xs4.y, Swy);
        Swz = fmaf(wp, xs4.z, Swz);
    }

    // ---- reduce over the 16 c-lanes within each group ----
#pragma unroll
    for (int off = 1; off < 16; off <<= 1) {
        g0 += __shfl_xor(g0, off, 64);
        g1 += __shfl_xor(g1, off, 64);
        g2 += __shfl_xor(g2, off, 64);
        g3 += __shfl_xor(g3, off, 64);
        Sw  += __shfl_xor(Sw,  off, 64);
        Swx += __shfl_xor(Swx, off, 64);
        Swy += __shfl_xor(Swy, off, 64);
        Swz += __shfl_xor(Swz, off, 64);
    }
    // group g holds g[outfeat 4g+r]; one lane per group stages to LDS
    if ((lane & 15) == 0) {
        *(float4*)&sg[w][4 * g] = make_float4(g0, g1, g2, g3);
    }

    // ---- node epilogue (lanes 0..15; group 0 has full Sw/Swx/y/z) ----
    if (lane < 16) {
        const int f = lane;
        float hd = bh1[l * NF + f];
        float hv = 0.f;
#pragma unroll
        for (int k = 0; k < NF; ++k) {
            const float hjk = shj[w][k];
            hd = fmaf(hjk, sWh1[k][f], hd);
            hv = fmaf(hjk, W_v[l * NF + k], hv);
        }
#pragma unroll
        for (int k = 0; k < NF; ++k) {
            hd = fmaf(sg[w][k], sWh1[NF + k][f], hd);
        }
        h_out[((size_t)b * NN + j) * NF + f] = shj[w][f] + fmaxf(hd, 0.f);

        if (f < 3) {
            const float xc = (f == 0) ? xj.x : ((f == 1) ? xj.y : xj.z);
            const float Sc = (f == 0) ? Swx  : ((f == 1) ? Swy  : Swz);
            const float agg = (Sw * xc - Sc) * (1.f / 255.f);
            const float vcomp = vs[((size_t)b * NN + j) * 3 + f];
            const float xnew = xc + agg + vcomp * hv;
            if (final_layer) x_out[((size_t)b * NN + j) * 3 + f] = xnew;
            else             x_out[((size_t)b * NN + j) * 4 + f] = xnew;
        }
        if (!final_layer && f == 3) x_out[((size_t)b * NN + j) * 4 + 3] = 0.f;
    }
}

extern "C" void kernel_launch(void* const* d_in, const int* in_sizes, int n_in,
                              void* d_out, int out_size, void* d_ws, size_t ws_size,
                              hipStream_t stream) {
    const float* xs      = (const float*)d_in[0];
    const float* vs      = (const float*)d_in[1];
    const float* charges = (const float*)d_in[2];
    const float* W_in    = (const float*)d_in[3];
    const float* b_in    = (const float*)d_in[4];
    const float* W_v     = (const float*)d_in[5];
    const float* We1     = (const float*)d_in[6];
    const float* be1     = (const float*)d_in[7];
    const float* We2     = (const float*)d_in[8];
    const float* be2     = (const float*)d_in[9];
    const float* Wx      = (const float*)d_in[10];
    const float* Wh1     = (const float*)d_in[11];
    const float* bh1     = (const float*)d_in[12];
    // d_in[13]=src, d_in[14]=dst: fully-connected pattern, computed analytically.

    float* ws = (float*)d_ws;
    float* x0 = ws;
    float* x1 = ws + 32768;
    float* h0 = ws + 65536;
    float* h1 = ws + 196608;
    float* out = (float*)d_out;

    hipLaunchKernelGGL(init_kernel, dim3(32), dim3(256), 0, stream,
                       xs, charges, W_in, b_in, x0, h0);
    hipLaunchKernelGGL(layer_kernel, dim3(BB * 64), dim3(256), 0, stream,
                       x0, h0, x1, h1, vs, W_v, We1, be1, We2, be2, Wx, Wh1, bh1, 0, 0);
    hipLaunchKernelGGL(layer_kernel, dim3(BB * 64), dim3(256), 0, stream,
                       x1, h1, x0, h0, vs, W_v, We1, be1, We2, be2, Wx, Wh1, bh1, 1, 0);
    hipLaunchKernelGGL(layer_kernel, dim3(BB * 64), dim3(256), 0, stream,
                       x0, h0, out, h1, vs, W_v, We1, be1, We2, be2, Wx, Wh1, bh1, 2, 1);
}

// Round 6
// 141.588 us; speedup vs baseline: 8.1783x; 1.1053x over previous
//
#include <hip/hip_runtime.h>

#define BB 32
#define NN 256
#define NF 16

typedef _Float16 half4 __attribute__((ext_vector_type(4)));
typedef float f32x4 __attribute__((ext_vector_type(4)));

// ws layout (floats):
//   x0  @ 0       [B][N][4]
//   x1  @ 32768   [B][N][4]
//   h0  @ 65536   [B][N][16]
//   h1  @ 196608  [B][N][16]
//   su0 @ 327680  [B][N][16]   u_i = h_i @ Wsrc(l)
//   sv0 @ 458752  [B][N][16]   v_i = be1(l) + h_i @ Wdst(l)
//   su1 @ 589824, sv1 @ 720896, su2 @ 851968, sv2 @ 983040
#define X0_OFF 0
#define X1_OFF 32768
#define H0_OFF 65536
#define H1_OFF 196608
#define SU0_OFF 327680
#define SV0_OFF 458752
#define SU1_OFF 589824
#define SV1_OFF 720896
#define SU2_OFF 851968
#define SV2_OFF 983040

// init: h0 = relu(charges*W_in + b_in); pad x; su0/sv0 for layer 0.
__global__ __launch_bounds__(256)
void init_kernel(const float* __restrict__ xs, const float* __restrict__ charges,
                 const float* __restrict__ W_in, const float* __restrict__ b_in,
                 const float* __restrict__ We1, const float* __restrict__ be1,
                 float* __restrict__ x0, float* __restrict__ h0,
                 float* __restrict__ su0, float* __restrict__ sv0) {
    __shared__ float sWs[256], sWd[256], sb1[NF];
    const int tid = threadIdx.x;
    sWs[tid] = We1[tid];
    sWd[tid] = We1[256 + tid];
    if (tid < NF) sb1[tid] = be1[tid];
    const int n = blockIdx.x * 256 + tid;
    const float c = charges[n];
    float h[NF];
#pragma unroll
    for (int f = 0; f < NF; ++f) {
        h[f] = fmaxf(fmaf(c, W_in[f], b_in[f]), 0.f);
        h0[n * NF + f] = h[f];
    }
    x0[n * 4 + 0] = xs[n * 3 + 0];
    x0[n * 4 + 1] = xs[n * 3 + 1];
    x0[n * 4 + 2] = xs[n * 3 + 2];
    x0[n * 4 + 3] = 0.f;
    __syncthreads();
#pragma unroll
    for (int k = 0; k < NF; ++k) {
        float u = 0.f, v = sb1[k];
#pragma unroll
        for (int f = 0; f < NF; ++f) {
            u = fmaf(h[f], sWs[f * NF + k], u);
            v = fmaf(h[f], sWd[f * NF + k], v);
        }
        su0[n * NF + k] = u;
        sv0[n * NF + k] = v;
    }
}

// 2048 blocks x 256 threads. Block = (batch b, dst-quad dg); wave w owns dst
// j = 4*dg + w. Per 16-src tile one v_mfma_f32_16x16x16f16 (lane (g,c)):
//   A-frag: We2[k=4g+i][outfeat=c]   B-frag: m1[src=16t+c][k=4g+i]
//   C-frag: m-hat[outfeat=4g+r][src=c]
// R6 changes vs R5: su/sv precomputed (no phase-B, no barriers before loop);
// su/x read straight from global (coalesced 1KB/tile, L2-resident, vmcnt-
// pipelined); Sw/Swx reductions hoisted out of the loop (no in-loop shuffles).
__global__ __launch_bounds__(256)
void layer_kernel(const float* __restrict__ x_in, const float* __restrict__ h_in,
                  const float* __restrict__ su_in, const float* __restrict__ sv_in,
                  float* __restrict__ x_out, float* __restrict__ h_out,
                  float* __restrict__ su_out, float* __restrict__ sv_out,
                  const float* __restrict__ vs, const float* __restrict__ Wv_l,
                  const float* __restrict__ We1_l, const float* __restrict__ We2_l,
                  const float* __restrict__ be2_l, const float* __restrict__ Wx_l,
                  const float* __restrict__ Wh1_l, const float* __restrict__ bh1_l,
                  const float* __restrict__ We1_n, const float* __restrict__ be1_n,
                  int final_layer) {
    __shared__ float sWh1[2 * NF][NF];     // 2 KB  (h-update weights)
    __shared__ float sWsT[NF][NF];         // 1 KB  (next layer Wsrc, transposed)
    __shared__ float sWdT[NF][NF];         // 1 KB  (next layer Wdst, transposed)
    __shared__ float sbe1n[NF];
    __shared__ float sh_new[4][NF + 1];
    __shared__ float sg[4][NF];

    const int tid  = threadIdx.x;
    const int b    = blockIdx.x >> 6;
    const int dg   = blockIdx.x & 63;
    const int w    = tid >> 6;
    const int lane = tid & 63;
    const int c    = lane & 15;
    const int g    = lane >> 4;
    const int j    = 4 * dg + w;

    // stage epilogue weights (not needed until after the loop; barrier is late)
    ((float*)sWh1)[tid]       = Wh1_l[tid];
    ((float*)sWh1)[256 + tid] = Wh1_l[256 + tid];
    {
        const int f = tid >> 4, k = tid & 15;
        sWsT[k][f] = We1_n[tid];
        sWdT[k][f] = We1_n[256 + tid];
    }
    if (tid < NF) sbe1n[tid] = be1_n[tid];

    // per-wave invariants
    const float* x_b  = x_in + (size_t)b * NN * 4;
    const float* su_b = su_in + (size_t)b * NN * NF;
    const float4 xj   = *(const float4*)(x_b + 4 * j);
    half4 afrag;
    afrag.x = (_Float16)We2_l[(4 * g + 0) * NF + c];
    afrag.y = (_Float16)We2_l[(4 * g + 1) * NF + c];
    afrag.z = (_Float16)We2_l[(4 * g + 2) * NF + c];
    afrag.w = (_Float16)We2_l[(4 * g + 3) * NF + c];
    const float4 v4   = *(const float4*)(sv_in + (size_t)b * NN * NF + j * NF + 4 * g);
    const float4 wr4  = *(const float4*)(We1_l + 512 + 4 * g);
    const float4 be2f = *(const float4*)(be2_l + 4 * g);
    const float4 wxf  = *(const float4*)(Wx_l + 4 * g);

    float Sw = 0.f, Swx = 0.f, Swy = 0.f, Swz = 0.f;
    float g0 = 0.f, g1 = 0.f, g2 = 0.f, g3 = 0.f;

    const float* su_p = su_b + c * NF + 4 * g;   // advance 256 floats/tile
    const float* x_p  = x_b + 4 * c;             // advance 64 floats/tile

#pragma unroll 2
    for (int t = 0; t < 16; ++t) {
        const float4 u4  = *(const float4*)(su_p + 256 * t);
        const float4 xs4 = *(const float4*)(x_p + 64 * t);
        const float dx = xj.x - xs4.x, dy = xj.y - xs4.y, dz = xj.z - xs4.z;
        const float r2 = fmaf(dx, dx, fmaf(dy, dy, dz * dz));
        const float m0 = fmaxf(fmaf(r2, wr4.x, u4.x + v4.x), 0.f);
        const float m1 = fmaxf(fmaf(r2, wr4.y, u4.y + v4.y), 0.f);
        const float m2 = fmaxf(fmaf(r2, wr4.z, u4.z + v4.z), 0.f);
        const float m3 = fmaxf(fmaf(r2, wr4.w, u4.w + v4.w), 0.f);
        half4 bfrag;
        bfrag.x = (_Float16)m0; bfrag.y = (_Float16)m1;
        bfrag.z = (_Float16)m2; bfrag.w = (_Float16)m3;
        const f32x4 zc = {0.f, 0.f, 0.f, 0.f};
        const f32x4 acc = __builtin_amdgcn_mfma_f32_16x16x16f16(afrag, bfrag, zc, 0, 0, 0);
        const float e0 = fmaxf(acc.x + be2f.x, 0.f);
        const float e1 = fmaxf(acc.y + be2f.y, 0.f);
        const float e2 = fmaxf(acc.z + be2f.z, 0.f);
        const float e3 = fmaxf(acc.w + be2f.w, 0.f);
        // group-partial of w (reduced across g AFTER the loop, not in-loop)
        float wp = e0 * wxf.x;
        wp = fmaf(e1, wxf.y, wp);
        wp = fmaf(e2, wxf.z, wp);
        wp = fmaf(e3, wxf.w, wp);
        const float gsel = ((16 * t + c) != j) ? 1.f : 0.f;
        g0 = fmaf(e0, gsel, g0);
        g1 = fmaf(e1, gsel, g1);
        g2 = fmaf(e2, gsel, g2);
        g3 = fmaf(e3, gsel, g3);
        Sw += wp;
        Swx = fmaf(wp, xs4.x, Swx);
        Swy = fmaf(wp, xs4.y, Swy);
        Swz = fmaf(wp, xs4.z, Swz);
    }

    // ---- out-of-loop reductions ----
    // Sw/Swx/y/z: sum over all 64 lanes (partials span both c and g dims)
#pragma unroll
    for (int off = 1; off < 64; off <<= 1) {
        Sw  += __shfl_xor(Sw,  off, 64);
        Swx += __shfl_xor(Swx, off, 64);
        Swy += __shfl_xor(Swy, off, 64);
        Swz += __shfl_xor(Swz, off, 64);
    }
    // g: sum over c-lanes within each g group
#pragma unroll
    for (int off = 1; off < 16; off <<= 1) {
        g0 += __shfl_xor(g0, off, 64);
        g1 += __shfl_xor(g1, off, 64);
        g2 += __shfl_xor(g2, off, 64);
        g3 += __shfl_xor(g3, off, 64);
    }
    if ((lane & 15) == 0) {
        *(float4*)&sg[w][4 * g] = make_float4(g0, g1, g2, g3);
    }
    __syncthreads();

    // ---- node epilogue (lanes 0..15 of each wave) ----
    if (lane < 16) {
        const int f = lane;
        float hd = bh1_l[f];
        float hv = 0.f;
#pragma unroll
        for (int k = 0; k < NF; ++k) {
            const float hjk = h_in[((size_t)b * NN + j) * NF + k];
            hd = fmaf(hjk, sWh1[k][f], hd);
            hv = fmaf(hjk, Wv_l[k], hv);
        }
#pragma unroll
        for (int k = 0; k < NF; ++k) {
            hd = fmaf(sg[w][k], sWh1[NF + k][f], hd);
        }
        const float hnew = h_in[((size_t)b * NN + j) * NF + f] + fmaxf(hd, 0.f);
        h_out[((size_t)b * NN + j) * NF + f] = hnew;
        sh_new[w][f] = hnew;

        if (f < 3) {
            const float xc = (f == 0) ? xj.x : ((f == 1) ? xj.y : xj.z);
            const float Sc = (f == 0) ? Swx  : ((f == 1) ? Swy  : Swz);
            const float agg = (Sw * xc - Sc) * (1.f / 255.f);
            const float vcomp = vs[((size_t)b * NN + j) * 3 + f];
            const float xnew = xc + agg + vcomp * hv;
            if (final_layer) x_out[((size_t)b * NN + j) * 3 + f] = xnew;
            else             x_out[((size_t)b * NN + j) * 4 + f] = xnew;
        }
        if (!final_layer && f == 3) x_out[((size_t)b * NN + j) * 4 + 3] = 0.f;
    }
    __syncthreads();

    // ---- su/sv for the NEXT layer (this block's 4 dst nodes) ----
    if (!final_layer && tid < 64) {
        const int jd = tid >> 4, k = tid & 15;
        const int jj = 4 * dg + jd;
        float u = 0.f, v = sbe1n[k];
#pragma unroll
        for (int f = 0; f < NF; ++f) {
            const float hf = sh_new[jd][f];
            u = fmaf(hf, sWsT[k][f], u);
            v = fmaf(hf, sWdT[k][f], v);
        }
        su_out[((size_t)b * NN + jj) * NF + k] = u;
        sv_out[((size_t)b * NN + jj) * NF + k] = v;
    }
}

extern "C" void kernel_launch(void* const* d_in, const int* in_sizes, int n_in,
                              void* d_out, int out_size, void* d_ws, size_t ws_size,
                              hipStream_t stream) {
    const float* xs      = (const float*)d_in[0];
    const float* vs      = (const float*)d_in[1];
    const float* charges = (const float*)d_in[2];
    const float* W_in    = (const float*)d_in[3];
    const float* b_in    = (const float*)d_in[4];
    const float* W_v     = (const float*)d_in[5];
    const float* We1     = (const float*)d_in[6];
    const float* be1     = (const float*)d_in[7];
    const float* We2     = (const float*)d_in[8];
    const float* be2     = (const float*)d_in[9];
    const float* Wx      = (const float*)d_in[10];
    const float* Wh1     = (const float*)d_in[11];
    const float* bh1     = (const float*)d_in[12];
    // d_in[13]=src, d_in[14]=dst: fully-connected pattern, computed analytically.

    float* ws = (float*)d_ws;
    float* x0  = ws + X0_OFF;
    float* x1  = ws + X1_OFF;
    float* h0  = ws + H0_OFF;
    float* h1  = ws + H1_OFF;
    float* su0 = ws + SU0_OFF;
    float* sv0 = ws + SV0_OFF;
    float* su1 = ws + SU1_OFF;
    float* sv1 = ws + SV1_OFF;
    float* su2 = ws + SU2_OFF;
    float* sv2 = ws + SV2_OFF;
    float* out = (float*)d_out;

    hipLaunchKernelGGL(init_kernel, dim3(32), dim3(256), 0, stream,
                       xs, charges, W_in, b_in, We1, be1, x0, h0, su0, sv0);
    // layer 0: x0,h0,su0,sv0 -> x1,h1,su1,sv1 (next-layer weights = l=1)
    hipLaunchKernelGGL(layer_kernel, dim3(2048), dim3(256), 0, stream,
                       x0, h0, su0, sv0, x1, h1, su1, sv1,
                       vs, W_v + 0 * 16, We1 + 0 * 528, We2 + 0 * 256,
                       be2 + 0 * 16, Wx + 0 * 16, Wh1 + 0 * 512, bh1 + 0 * 16,
                       We1 + 1 * 528, be1 + 1 * 16, 0);
    // layer 1: x1,h1,su1,sv1 -> x0,h0,su2,sv2 (next-layer weights = l=2)
    hipLaunchKernelGGL(layer_kernel, dim3(2048), dim3(256), 0, stream,
                       x1, h1, su1, sv1, x0, h0, su2, sv2,
                       vs, W_v + 1 * 16, We1 + 1 * 528, We2 + 1 * 256,
                       be2 + 1 * 16, Wx + 1 * 16, Wh1 + 1 * 512, bh1 + 1 * 16,
                       We1 + 2 * 528, be1 + 2 * 16, 0);
    // layer 2 (final): x0,h0,su2,sv2 -> out (h/su/sv next unused)
    hipLaunchKernelGGL(layer_kernel, dim3(2048), dim3(256), 0, stream,
                       x0, h0, su2, sv2, out, h1, su1, sv1,
                       vs, W_v + 2 * 16, We1 + 2 * 528, We2 + 2 * 256,
                       be2 + 2 * 16, Wx + 2 * 16, Wh1 + 2 * 512, bh1 + 2 * 16,
                       We1 + 2 * 528, be1 + 2 * 16, 1);
}

// Round 8
// 135.734 us; speedup vs baseline: 8.5310x; 1.0431x over previous
//
#include <hip/hip_runtime.h>

#define BB 32
#define NN 256
#define NF 16

typedef _Float16 half4 __attribute__((ext_vector_type(4)));
typedef float f32x4 __attribute__((ext_vector_type(4)));

// ws layout (floats): ping-pong x/h/su/sv
#define X0_OFF 0
#define X1_OFF 32768
#define H0_OFF 65536
#define H1_OFF 196608
#define SU0_OFF 327680
#define SV0_OFF 458752
#define SU1_OFF 589824
#define SV1_OFF 720896
#define SU2_OFF 851968
#define SV2_OFF 983040

// init: h0 = relu(charges*W_in + b_in); pad x; su0/sv0 for layer 0.
__global__ __launch_bounds__(256)
void init_kernel(const float* __restrict__ xs, const float* __restrict__ charges,
                 const float* __restrict__ W_in, const float* __restrict__ b_in,
                 const float* __restrict__ We1, const float* __restrict__ be1,
                 float* __restrict__ x0, float* __restrict__ h0,
                 float* __restrict__ su0, float* __restrict__ sv0) {
    __shared__ float sWs[256], sWd[256], sb1[NF];
    const int tid = threadIdx.x;
    sWs[tid] = We1[tid];
    sWd[tid] = We1[256 + tid];
    if (tid < NF) sb1[tid] = be1[tid];
    const int n = blockIdx.x * 256 + tid;
    const float c = charges[n];
    float h[NF];
#pragma unroll
    for (int f = 0; f < NF; ++f) {
        h[f] = fmaxf(fmaf(c, W_in[f], b_in[f]), 0.f);
        h0[n * NF + f] = h[f];
    }
    x0[n * 4 + 0] = xs[n * 3 + 0];
    x0[n * 4 + 1] = xs[n * 3 + 1];
    x0[n * 4 + 2] = xs[n * 3 + 2];
    x0[n * 4 + 3] = 0.f;
    __syncthreads();
#pragma unroll
    for (int k = 0; k < NF; ++k) {
        float u = 0.f, v = sb1[k];
#pragma unroll
        for (int f = 0; f < NF; ++f) {
            u = fmaf(h[f], sWs[f * NF + k], u);
            v = fmaf(h[f], sWd[f * NF + k], v);
        }
        su0[n * NF + k] = u;
        sv0[n * NF + k] = v;
    }
}

// 1024 blocks x 256 threads. Block = (batch b, node-octet oct); wave w owns
// dsts j0 = 8*oct+w and j1 = 8*oct+4+w, sharing each tile's u4/xs4 loads
// across both dsts (halves per-dst VMEM traffic & latency exposure vs R6).
// Per 16-src tile, per dst, one v_mfma_f32_16x16x16f16 (lane (g,c)):
//   A-frag: We2[k=4g+i][outfeat=c]   B-frag: m1[src=16t+c][k=4g+i]
//   C-frag: m-hat[outfeat=4g+r][src=c]   — math identical to validated R6.
__global__ __launch_bounds__(256)
void layer_kernel(const float* __restrict__ x_in, const float* __restrict__ h_in,
                  const float* __restrict__ su_in, const float* __restrict__ sv_in,
                  float* __restrict__ x_out, float* __restrict__ h_out,
                  float* __restrict__ su_out, float* __restrict__ sv_out,
                  const float* __restrict__ vs, const float* __restrict__ Wv_l,
                  const float* __restrict__ We1_l, const float* __restrict__ We2_l,
                  const float* __restrict__ be2_l, const float* __restrict__ Wx_l,
                  const float* __restrict__ Wh1_l, const float* __restrict__ bh1_l,
                  const float* __restrict__ We1_n, const float* __restrict__ be1_n,
                  int final_layer) {
    __shared__ float sWh1s[512];
    __shared__ float sWa[256];            // next-layer WsrcT
    __shared__ float sWb[256];            // next-layer WdstT
    __shared__ float sbe1n[NF];
    __shared__ float sh_new[8][NF + 1];
    __shared__ float sg[8][NF];

    const int tid  = threadIdx.x;
    const int b    = blockIdx.x >> 5;
    const int oct  = blockIdx.x & 31;
    const int n0l  = 8 * oct;
    const size_t n0 = (size_t)b * NN + n0l;
    const int w    = tid >> 6;
    const int lane = tid & 63;
    const int c    = lane & 15;
    const int g    = lane >> 4;

    // stage epilogue/next-layer weights (consumed only after the post-loop sync)
    sWh1s[tid]       = Wh1_l[tid];
    sWh1s[256 + tid] = Wh1_l[256 + tid];
    if (!final_layer) {
        const int f = tid >> 4, k = tid & 15;
        sWa[k * NF + f] = We1_n[tid];           // WsrcT
        sWb[k * NF + f] = We1_n[256 + tid];     // WdstT
        if (tid < NF) sbe1n[tid] = be1_n[tid];
    }

    // per-wave invariants for dsts j0, j1
    const int j0 = n0l + w, j1 = n0l + 4 + w;
    const float* x_b  = x_in + (size_t)b * NN * 4;
    const float* su_b = su_in + (size_t)b * NN * NF;
    const float4 xj0 = *(const float4*)(x_b + 4 * j0);
    const float4 xj1 = *(const float4*)(x_b + 4 * j1);
    half4 afrag;
    afrag.x = (_Float16)We2_l[(4 * g + 0) * NF + c];
    afrag.y = (_Float16)We2_l[(4 * g + 1) * NF + c];
    afrag.z = (_Float16)We2_l[(4 * g + 2) * NF + c];
    afrag.w = (_Float16)We2_l[(4 * g + 3) * NF + c];
    const float4 v40  = *(const float4*)(sv_in + ((size_t)b * NN + j0) * NF + 4 * g);
    const float4 v41  = *(const float4*)(sv_in + ((size_t)b * NN + j1) * NF + 4 * g);
    const float4 wr4  = *(const float4*)(We1_l + 512 + 4 * g);
    const float4 be2f = *(const float4*)(be2_l + 4 * g);
    const float4 wxf  = *(const float4*)(Wx_l + 4 * g);

    float Sw0 = 0.f, Swx0 = 0.f, Swy0 = 0.f, Swz0 = 0.f;
    float Sw1 = 0.f, Swx1 = 0.f, Swy1 = 0.f, Swz1 = 0.f;
    float g00 = 0.f, g01 = 0.f, g02 = 0.f, g03 = 0.f;
    float g10 = 0.f, g11 = 0.f, g12 = 0.f, g13 = 0.f;

    const float* su_p = su_b + c * NF + 4 * g;   // +256 floats per tile
    const float* x_p  = x_b + 4 * c;             // +64 floats per tile

#pragma unroll 2
    for (int t = 0; t < 16; ++t) {
        const float4 u4  = *(const float4*)(su_p + 256 * t);
        const float4 xs4 = *(const float4*)(x_p + 64 * t);
        const f32x4 zc = {0.f, 0.f, 0.f, 0.f};
        const int s = 16 * t + c;
        // ---- dst 0 ----
        {
            const float dx = xj0.x - xs4.x, dy = xj0.y - xs4.y, dz = xj0.z - xs4.z;
            const float r2 = fmaf(dx, dx, fmaf(dy, dy, dz * dz));
            const float m0 = fmaxf(fmaf(r2, wr4.x, u4.x + v40.x), 0.f);
            const float m1 = fmaxf(fmaf(r2, wr4.y, u4.y + v40.y), 0.f);
            const float m2 = fmaxf(fmaf(r2, wr4.z, u4.z + v40.z), 0.f);
            const float m3 = fmaxf(fmaf(r2, wr4.w, u4.w + v40.w), 0.f);
            half4 bfrag;
            bfrag.x = (_Float16)m0; bfrag.y = (_Float16)m1;
            bfrag.z = (_Float16)m2; bfrag.w = (_Float16)m3;
            const f32x4 acc = __builtin_amdgcn_mfma_f32_16x16x16f16(afrag, bfrag, zc, 0, 0, 0);
            const float e0 = fmaxf(acc.x + be2f.x, 0.f);
            const float e1 = fmaxf(acc.y + be2f.y, 0.f);
            const float e2 = fmaxf(acc.z + be2f.z, 0.f);
            const float e3 = fmaxf(acc.w + be2f.w, 0.f);
            float wp = e0 * wxf.x;
            wp = fmaf(e1, wxf.y, wp);
            wp = fmaf(e2, wxf.z, wp);
            wp = fmaf(e3, wxf.w, wp);
            const float gsel = (s != j0) ? 1.f : 0.f;
            g00 = fmaf(e0, gsel, g00);
            g01 = fmaf(e1, gsel, g01);
            g02 = fmaf(e2, gsel, g02);
            g03 = fmaf(e3, gsel, g03);
            Sw0 += wp;
            Swx0 = fmaf(wp, xs4.x, Swx0);
            Swy0 = fmaf(wp, xs4.y, Swy0);
            Swz0 = fmaf(wp, xs4.z, Swz0);
        }
        // ---- dst 1 (reuses u4/xs4) ----
        {
            const float dx = xj1.x - xs4.x, dy = xj1.y - xs4.y, dz = xj1.z - xs4.z;
            const float r2 = fmaf(dx, dx, fmaf(dy, dy, dz * dz));
            const float m0 = fmaxf(fmaf(r2, wr4.x, u4.x + v41.x), 0.f);
            const float m1 = fmaxf(fmaf(r2, wr4.y, u4.y + v41.y), 0.f);
            const float m2 = fmaxf(fmaf(r2, wr4.z, u4.z + v41.z), 0.f);
            const float m3 = fmaxf(fmaf(r2, wr4.w, u4.w + v41.w), 0.f);
            half4 bfrag;
            bfrag.x = (_Float16)m0; bfrag.y = (_Float16)m1;
            bfrag.z = (_Float16)m2; bfrag.w = (_Float16)m3;
            const f32x4 acc = __builtin_amdgcn_mfma_f32_16x16x16f16(afrag, bfrag, zc, 0, 0, 0);
            const float e0 = fmaxf(acc.x + be2f.x, 0.f);
            const float e1 = fmaxf(acc.y + be2f.y, 0.f);
            const float e2 = fmaxf(acc.z + be2f.z, 0.f);
            const float e3 = fmaxf(acc.w + be2f.w, 0.f);
            float wp = e0 * wxf.x;
            wp = fmaf(e1, wxf.y, wp);
            wp = fmaf(e2, wxf.z, wp);
            wp = fmaf(e3, wxf.w, wp);
            const float gsel = (s != j1) ? 1.f : 0.f;
            g10 = fmaf(e0, gsel, g10);
            g11 = fmaf(e1, gsel, g11);
            g12 = fmaf(e2, gsel, g12);
            g13 = fmaf(e3, gsel, g13);
            Sw1 += wp;
            Swx1 = fmaf(wp, xs4.x, Swx1);
            Swy1 = fmaf(wp, xs4.y, Swy1);
            Swz1 = fmaf(wp, xs4.z, Swz1);
        }
    }

    // ---- out-of-loop reductions ----
#pragma unroll
    for (int off = 1; off < 64; off <<= 1) {
        Sw0  += __shfl_xor(Sw0,  off, 64);  Sw1  += __shfl_xor(Sw1,  off, 64);
        Swx0 += __shfl_xor(Swx0, off, 64);  Swx1 += __shfl_xor(Swx1, off, 64);
        Swy0 += __shfl_xor(Swy0, off, 64);  Swy1 += __shfl_xor(Swy1, off, 64);
        Swz0 += __shfl_xor(Swz0, off, 64);  Swz1 += __shfl_xor(Swz1, off, 64);
    }
#pragma unroll
    for (int off = 1; off < 16; off <<= 1) {
        g00 += __shfl_xor(g00, off, 64);  g10 += __shfl_xor(g10, off, 64);
        g01 += __shfl_xor(g01, off, 64);  g11 += __shfl_xor(g11, off, 64);
        g02 += __shfl_xor(g02, off, 64);  g12 += __shfl_xor(g12, off, 64);
        g03 += __shfl_xor(g03, off, 64);  g13 += __shfl_xor(g13, off, 64);
    }
    if ((lane & 15) == 0) {
        *(float4*)&sg[w][4 * g]     = make_float4(g00, g01, g02, g03);
        *(float4*)&sg[w + 4][4 * g] = make_float4(g10, g11, g12, g13);
    }
    __syncthreads();

    // node epilogue: lanes 0..15 -> j0 (slot w); lanes 32..47 -> j1 (slot w+4)
    const int is0 = (lane < 16);
    const int is1 = (lane >= 32 && lane < 48);
    if (is0 || is1) {
        const int f = lane & 15;
        const int slot = is0 ? w : (w + 4);
        const int jm   = is0 ? j0 : j1;
        const float SwS = is0 ? Sw0  : Sw1;
        const float SxS = is0 ? Swx0 : Swx1;
        const float SyS = is0 ? Swy0 : Swy1;
        const float SzS = is0 ? Swz0 : Swz1;
        const float4 xjm = is0 ? xj0 : xj1;
        const size_t nj = (size_t)b * NN + jm;
        float hd = bh1_l[f];
        float hv = 0.f;
#pragma unroll
        for (int k = 0; k < NF; ++k) {
            const float hjk = h_in[nj * NF + k];
            hd = fmaf(hjk, sWh1s[k * NF + f], hd);
            hv = fmaf(hjk, Wv_l[k], hv);
        }
#pragma unroll
        for (int k = 0; k < NF; ++k) {
            hd = fmaf(sg[slot][k], sWh1s[(NF + k) * NF + f], hd);
        }
        const float hnew = h_in[nj * NF + f] + fmaxf(hd, 0.f);
        sh_new[slot][f] = hnew;
        if (!final_layer) h_out[nj * NF + f] = hnew;
        if (f < 3) {
            const float xc = (f == 0) ? xjm.x : ((f == 1) ? xjm.y : xjm.z);
            const float Sc = (f == 0) ? SxS  : ((f == 1) ? SyS  : SzS);
            const float agg = (SwS * xc - Sc) * (1.f / 255.f);
            const float xnew = xc + agg + vs[nj * 3 + f] * hv;
            if (final_layer) x_out[nj * 3 + f] = xnew;
            else             x_out[nj * 4 + f] = xnew;
        }
        if (!final_layer && f == 3) x_out[nj * 4 + 3] = 0.f;
    }

    if (!final_layer) {
        __syncthreads();
        // su/sv for the NEXT layer (this block's 8 nodes)
        if (tid < 128) {
            const int jd = tid >> 4, k = tid & 15;
            float u = 0.f, v = sbe1n[k];
#pragma unroll
            for (int f = 0; f < NF; ++f) {
                const float hf = sh_new[jd][f];
                u = fmaf(hf, sWa[k * NF + f], u);
                v = fmaf(hf, sWb[k * NF + f], v);
            }
            su_out[(n0 + jd) * NF + k] = u;
            sv_out[(n0 + jd) * NF + k] = v;
        }
    }
}

extern "C" void kernel_launch(void* const* d_in, const int* in_sizes, int n_in,
                              void* d_out, int out_size, void* d_ws, size_t ws_size,
                              hipStream_t stream) {
    const float* xs      = (const float*)d_in[0];
    const float* vs      = (const float*)d_in[1];
    const float* charges = (const float*)d_in[2];
    const float* W_in    = (const float*)d_in[3];
    const float* b_in    = (const float*)d_in[4];
    const float* W_v     = (const float*)d_in[5];
    const float* We1     = (const float*)d_in[6];
    const float* be1     = (const float*)d_in[7];
    const float* We2     = (const float*)d_in[8];
    const float* be2     = (const float*)d_in[9];
    const float* Wx      = (const float*)d_in[10];
    const float* Wh1     = (const float*)d_in[11];
    const float* bh1     = (const float*)d_in[12];
    // d_in[13]=src, d_in[14]=dst: fully-connected pattern, computed analytically.

    float* ws = (float*)d_ws;
    float* x0  = ws + X0_OFF;
    float* x1  = ws + X1_OFF;
    float* h0  = ws + H0_OFF;
    float* h1  = ws + H1_OFF;
    float* su0 = ws + SU0_OFF;
    float* sv0 = ws + SV0_OFF;
    float* su1 = ws + SU1_OFF;
    float* sv1 = ws + SV1_OFF;
    float* su2 = ws + SU2_OFF;
    float* sv2 = ws + SV2_OFF;
    float* out = (float*)d_out;

    hipLaunchKernelGGL(init_kernel, dim3(32), dim3(256), 0, stream,
                       xs, charges, W_in, b_in, We1, be1, x0, h0, su0, sv0);
    hipLaunchKernelGGL(layer_kernel, dim3(1024), dim3(256), 0, stream,
                       x0, h0, su0, sv0, x1, h1, su1, sv1,
                       vs, W_v + 0 * 16, We1 + 0 * 528, We2 + 0 * 256,
                       be2 + 0 * 16, Wx + 0 * 16, Wh1 + 0 * 512, bh1 + 0 * 16,
                       We1 + 1 * 528, be1 + 1 * 16, 0);
    hipLaunchKernelGGL(layer_kernel, dim3(1024), dim3(256), 0, stream,
                       x1, h1, su1, sv1, x0, h0, su2, sv2,
                       vs, W_v + 1 * 16, We1 + 1 * 528, We2 + 1 * 256,
                       be2 + 1 * 16, Wx + 1 * 16, Wh1 + 1 * 512, bh1 + 1 * 16,
                       We1 + 2 * 528, be1 + 2 * 16, 0);
    hipLaunchKernelGGL(layer_kernel, dim3(1024), dim3(256), 0, stream,
                       x0, h0, su2, sv2, out, h1, su1, sv1,
                       vs, W_v + 2 * 16, We1 + 2 * 528, We2 + 2 * 256,
                       be2 + 2 * 16, Wx + 2 * 16, Wh1 + 2 * 512, bh1 + 2 * 16,
                       We1 + 2 * 528, be1 + 2 * 16, 1);
}